// Round 15
// baseline (66.018 us; speedup 1.0000x reference)
//
#include <hip/hip_runtime.h>

// Problem constants (B=8, K=32 -> N=256 patches; C=3; H=W=128)
#define HH 128
#define WW 128
#define HW (HH * WW)
#define BAND 16            // output rows per patch block
#define TROWS 20           // intermediate rows per band (<=19 used)
#define SRC_ROWS 84        // staged source rows (worst span <=82)

// ---------------------------------------------------------------------------
// Verified-correct arithmetic (R9-R14, passed):
//  - trig: correctly-rounded f32 cos/sin (f64 libm, rounded once)
//  - rotation einsum: XLA FMA lowering: gx=fma(-s,y,fl(c*x)), gy=fma(c,y,fl(s*x))
//  - scale einsum: fl(sc*x); pix chain stepwise; rintf half-even; OOB->0
//  - flip folded into pass-1 coords (exact dyadic sign flip)
//  - branchless clamped gathers: OOB corner = +0 == 0.0f, bit-same
// This round: SAME arithmetic; source rows staged into LDS via coalesced
// float4 loads (row range from f32-monotone corner evaluation), so the
// rotated 4-tap gather hits LDS instead of splitting into ~25 L1
// transactions per instruction.
// ---------------------------------------------------------------------------

__device__ __forceinline__ float norm_coord(int i) {
    return __fsub_rn(__fmul_rn((float)(2 * i + 1), 0.0078125f), 1.0f);
}

__device__ __forceinline__ float pix_coord(float g) {
    float t = __fadd_rn(g, 1.0f);
    t = __fmul_rn(t, 128.0f);
    t = __fsub_rn(t, 1.0f);
    return __fmul_rn(t, 0.5f);
}

__device__ __forceinline__ int clamp127(int v) {
    return v < 0 ? 0 : (v > 127 ? 127 : v);
}
__device__ __forceinline__ int iclamp(int v, int a, int b) {
    return v < a ? a : (v > b ? b : v);
}

// ---------------------------------------------------------------------------
// Single kernel. Blocks [0, NP): patch (slice, band). Blocks [NP, NP+NL):
// label chunks (8192 px each). Branch is block-uniform. 512 threads.
// ---------------------------------------------------------------------------
__global__ void __launch_bounds__(512, 6)
pa_all(const float* __restrict__ patches,
       const float* __restrict__ labels,
       const float* __restrict__ angles,
       const int* __restrict__ flip_h,
       const int* __restrict__ flip_v,
       const float* __restrict__ scales,
       float* __restrict__ out_p,
       float* __restrict__ out_l,
       int npatch_blocks) {
    __shared__ float src[SRC_ROWS * WW];    // 42 KB staged source rows
    __shared__ float tile[TROWS * WW];      // 10 KB pass-1 intermediate
    __shared__ float prm[5];
    int bid = blockIdx.x;
    int tid = threadIdx.x;
    bool is_patch = bid < npatch_blocks;
    int n = is_patch ? ((bid >> 3) / 3) : ((bid - npatch_blocks) >> 1);

    if (tid == 0) {
        double a = (double)angles[n];
        prm[0] = (float)cos(a);             // correctly-rounded f32
        prm[1] = (float)sin(a);
        prm[2] = flip_h[n] ? -1.0f : 1.0f;
        prm[3] = flip_v[n] ? -1.0f : 1.0f;
        prm[4] = scales[n];
    }
    __syncthreads();
    float c = prm[0], s = prm[1], fsx = prm[2], fsy = prm[3], sc = prm[4];

    if (is_patch) {
        int band = bid & 7;
        int slice = bid >> 3;               // n*3 + ch
        int r0 = band * BAND;

        // intermediate rows needed by pass 2 (monotone in h; R12-proven)
        float iy_lo = pix_coord(__fmul_rn(sc, norm_coord(r0)));
        float iy_hi = pix_coord(__fmul_rn(sc, norm_coord(r0 + BAND - 1)));
        int lo = (int)floorf(iy_lo);
        int hi = (int)floorf(iy_hi) + 1;
        lo = lo < 0 ? 0 : lo;
        hi = hi > 127 ? 127 : hi;
        int nrows = hi - lo + 1;            // <= 20

        // source rows needed by pass 1: corner evaluation of the EXACT tap
        // chain (f32 ops are monotone; extremes at the 4 corners)
        float xa = __fmul_rn(fsx, norm_coord(0));
        float xb = __fmul_rn(fsx, norm_coord(WW - 1));
        float sxa = __fmul_rn(s, xa), sxb = __fmul_rn(s, xb);
        float ya = __fmul_rn(fsy, norm_coord(lo));
        float yb = __fmul_rn(fsy, norm_coord(hi));
        float i1 = pix_coord(__fmaf_rn(c, ya, sxa));
        float i2 = pix_coord(__fmaf_rn(c, ya, sxb));
        float i3 = pix_coord(__fmaf_rn(c, yb, sxa));
        float i4 = pix_coord(__fmaf_rn(c, yb, sxb));
        float imin = fminf(fminf(i1, i2), fminf(i3, i4));
        float imax = fmaxf(fmaxf(i1, i2), fmaxf(i3, i4));
        int ymin = iclamp((int)floorf(imin), 0, 127);
        int ymax = iclamp((int)floorf(imax) + 1, 0, 127);
        int nsrc = ymax - ymin + 1;         // <= 82

        // ---- stage source rows [ymin, ymax] coalesced (float4) ----
        const float* img = patches + (size_t)slice * HW;
        const float4* gsrc = (const float4*)(img + ymin * WW);
        int n4 = nsrc * (WW / 4);
        for (int p = tid; p < n4; p += 512)
            ((float4*)src)[p] = gsrc[p];
        __syncthreads();

        // ---- pass 1: rotate+flip from LDS src -> tile ----
        int w = tid & (WW - 1);
        float x1n = __fmul_rn(fsx, norm_coord(w));   // exact sign flip
        float cx = __fmul_rn(c, x1n);
        float sx = __fmul_rn(s, x1n);
        #pragma unroll
        for (int i = 0; i < TROWS / 4; ++i) {        // 5 iters, 4 rows each
            int p = i * 512 + tid;
            int row = p >> 7;
            if (row < nrows) {
                int h = lo + row;
                float y = __fmul_rn(fsy, norm_coord(h));
                float ix = pix_coord(__fmaf_rn(-s, y, cx));
                float iy = pix_coord(__fmaf_rn(c, y, sx));
                float x0f = floorf(ix), y0f = floorf(iy);
                float wx1 = __fsub_rn(ix, x0f), wy1 = __fsub_rn(iy, y0f);
                float wx0 = __fsub_rn(1.0f, wx1), wy0 = __fsub_rn(1.0f, wy1);
                int x0 = (int)x0f, y0 = (int)y0f;
                int x1 = x0 + 1, y1 = y0 + 1;
                bool bx0 = (unsigned)x0 < 128u, bx1 = (unsigned)x1 < 128u;
                bool by0 = (unsigned)y0 < 128u, by1 = (unsigned)y1 < 128u;
                int xc0 = clamp127(x0), xc1 = clamp127(x1);
                // staged-row index (identity when in-bounds; proven by
                // corner monotonicity)
                int q0 = (iclamp(y0, ymin, ymax) - ymin) * WW;
                int q1 = (iclamp(y1, ymin, ymax) - ymin) * WW;
                float v00 = src[q0 + xc0];
                float v10 = src[q0 + xc1];
                float v01 = src[q1 + xc0];
                float v11 = src[q1 + xc1];
                v00 = (bx0 && by0) ? v00 : 0.0f;
                v10 = (bx1 && by0) ? v10 : 0.0f;
                v01 = (bx0 && by1) ? v01 : 0.0f;
                v11 = (bx1 && by1) ? v11 : 0.0f;
                float acc;
                acc = __fmul_rn(v00, __fmul_rn(wx0, wy0));
                acc = __fadd_rn(acc, __fmul_rn(v10, __fmul_rn(wx1, wy0)));
                acc = __fadd_rn(acc, __fmul_rn(v01, __fmul_rn(wx0, wy1)));
                acc = __fadd_rn(acc, __fmul_rn(v11, __fmul_rn(wx1, wy1)));
                tile[row * WW + w] = acc;
            }
        }
        __syncthreads();

        // ---- pass 2: scale from tile -> out (x-side hoisted) ----
        float ix = pix_coord(__fmul_rn(sc, norm_coord(w)));
        float x0f = floorf(ix);
        float wx1 = __fsub_rn(ix, x0f);
        float wx0 = __fsub_rn(1.0f, wx1);
        int x0 = (int)x0f, x1 = x0 + 1;
        bool bx0 = (unsigned)x0 < 128u, bx1 = (unsigned)x1 < 128u;
        int xc0 = clamp127(x0), xc1 = clamp127(x1);

        float* op = out_p + (size_t)slice * HW + r0 * WW;
        #pragma unroll
        for (int i = 0; i < BAND / 4; ++i) {         // 4 iters, 4 rows each
            int p = i * 512 + tid;
            int row = p >> 7;
            int h = r0 + row;
            float iy = pix_coord(__fmul_rn(sc, norm_coord(h)));
            float y0f = floorf(iy);
            float wy1 = __fsub_rn(iy, y0f);
            float wy0 = __fsub_rn(1.0f, wy1);
            float w00 = __fmul_rn(wx0, wy0), w10 = __fmul_rn(wx1, wy0);
            float w01 = __fmul_rn(wx0, wy1), w11 = __fmul_rn(wx1, wy1);
            int y0 = (int)y0f, y1 = y0 + 1;
            bool by0 = (unsigned)y0 < 128u, by1 = (unsigned)y1 < 128u;
            int t0 = (iclamp(y0, lo, hi) - lo) * WW;
            int t1 = (iclamp(y1, lo, hi) - lo) * WW;
            float v00 = tile[t0 + xc0];
            float v10 = tile[t0 + xc1];
            float v01 = tile[t1 + xc0];
            float v11 = tile[t1 + xc1];
            v00 = (bx0 && by0) ? v00 : 0.0f;
            v10 = (bx1 && by0) ? v10 : 0.0f;
            v01 = (bx0 && by1) ? v01 : 0.0f;
            v11 = (bx1 && by1) ? v11 : 0.0f;
            float acc;
            acc = __fmul_rn(v00, w00);
            acc = __fadd_rn(acc, __fmul_rn(v10, w10));
            acc = __fadd_rn(acc, __fmul_rn(v01, w01));
            acc = __fadd_rn(acc, __fmul_rn(v11, w11));
            op[row * WW + w] = acc;
        }
    } else {
        // ----- label path: fused nearest-of-nearest, 8192 px per block -----
        int lb = bid - npatch_blocks;
        const float* lab = labels + (size_t)n * HW;
        float* ol = out_l + (size_t)n * HW;

        int base = (lb & 1) * 8192;
        int w = tid & (WW - 1);
        float ix2 = pix_coord(__fmul_rn(sc, norm_coord(w)));
        float xr2 = rintf(ix2);
        bool okx2 = (xr2 >= 0.0f) && (xr2 <= 127.0f);
        int w2 = (int)xr2;
        float xw2 = okx2 ? __fmul_rn(fsx, norm_coord(w2)) : 0.0f;
        float cx = __fmul_rn(c, xw2);
        float sx = __fmul_rn(s, xw2);

        #pragma unroll 4
        for (int i = 0; i < 16; ++i) {
            int p = base + i * 512 + tid;
            int h = (p >> 7) & (HH - 1);
            float iy2 = pix_coord(__fmul_rn(sc, norm_coord(h)));
            float yr2 = rintf(iy2);
            float outv = 0.0f;
            if (okx2 && yr2 >= 0.0f && yr2 <= 127.0f) {
                int h2 = (int)yr2;
                float y = __fmul_rn(fsy, norm_coord(h2));
                float xr1 = rintf(pix_coord(__fmaf_rn(-s, y, cx)));
                float yr1 = rintf(pix_coord(__fmaf_rn(c, y, sx)));
                if (xr1 >= 0.0f && xr1 <= 127.0f &&
                    yr1 >= 0.0f && yr1 <= 127.0f) {
                    outv = lab[(int)yr1 * WW + (int)xr1];
                }
            }
            ol[p] = outv;
        }
    }
}

extern "C" void kernel_launch(void* const* d_in, const int* in_sizes, int n_in,
                              void* d_out, int out_size, void* d_ws, size_t ws_size,
                              hipStream_t stream) {
    const float* patches = (const float*)d_in[0];
    const float* labels  = (const float*)d_in[1];
    const float* angles  = (const float*)d_in[2];
    const int*   flip_h  = (const int*)d_in[3];
    const int*   flip_v  = (const int*)d_in[4];
    const float* scales  = (const float*)d_in[5];

    const int N = in_sizes[2];            // B*K = 256
    float* out   = (float*)d_out;
    float* out_p = out;                   // N*3*H*W
    float* out_l = out + (size_t)N * 3 * HW;

    int npatch_blocks = N * 3 * 8;        // 6144: (slice, 16-row band)
    int nlabel_blocks = N * 2;            // 512: 8192 px each
    pa_all<<<npatch_blocks + nlabel_blocks, 512, 0, stream>>>(
        patches, labels, angles, flip_h, flip_v, scales,
        out_p, out_l, npatch_blocks);
}

// Round 16
// 50.645 us; speedup vs baseline: 1.3035x; 1.3035x over previous
//
#include <hip/hip_runtime.h>

// Problem constants (B=8, K=32 -> N=256 patches; C=3; H=W=128)
#define HH 128
#define WW 128
#define HW (HH * WW)
#define BAND 16            // output rows per band
#define TROWS 20           // intermediate tile rows (max needed 19)

// ---------------------------------------------------------------------------
// Verified-correct arithmetic (R9-R15, passed):
//  - trig: correctly-rounded f32 cos/sin (f64 libm, rounded once)
//  - rotation einsum: XLA FMA lowering: gx=fma(-s,y,fl(c*x)), gy=fma(c,y,fl(s*x))
//  - scale einsum: fl(sc*x); pix chain stepwise; rintf half-even; OOB->0
//  - flip folded into pass-1 coords (exact dyadic sign flip)
//  - branchless clamped gathers: OOB corner = +0 == 0.0f, bit-same
// This round: SAME arithmetic; one block per slice stages the FULL 64 KB
// slice into LDS once (no fetch amplification, coalesced float4), then all
// 8 bands run in-block: pass-1 rotated gather from LDS src (diagonal access
// ~1 lane/bank), banded tile, pass-2 from tile. 74 KB LDS -> 2 blocks/CU
// x 16 waves = 32 waves/CU cap.
// ---------------------------------------------------------------------------

__device__ __forceinline__ float norm_coord(int i) {
    return __fsub_rn(__fmul_rn((float)(2 * i + 1), 0.0078125f), 1.0f);
}

__device__ __forceinline__ float pix_coord(float g) {
    float t = __fadd_rn(g, 1.0f);
    t = __fmul_rn(t, 128.0f);
    t = __fsub_rn(t, 1.0f);
    return __fmul_rn(t, 0.5f);
}

__device__ __forceinline__ int clamp127(int v) {
    return v < 0 ? 0 : (v > 127 ? 127 : v);
}
__device__ __forceinline__ int iclamp(int v, int a, int b) {
    return v < a ? a : (v > b ? b : v);
}

// ---------------------------------------------------------------------------
// Blocks [0, NP): one per channel slice (1024 thr). Blocks [NP, NP+N):
// one per label slice. Branch is block-uniform.
// ---------------------------------------------------------------------------
__global__ void __launch_bounds__(1024, 8)
pa_all(const float* __restrict__ patches,
       const float* __restrict__ labels,
       const float* __restrict__ angles,
       const int* __restrict__ flip_h,
       const int* __restrict__ flip_v,
       const float* __restrict__ scales,
       float* __restrict__ out_p,
       float* __restrict__ out_l,
       int npatch_blocks) {
    __shared__ float src[HW];               // 64 KB full source slice
    __shared__ float tile[TROWS * WW];      // 10 KB pass-1 intermediate band
    __shared__ float prm[5];
    int bid = blockIdx.x;
    int tid = threadIdx.x;
    bool is_patch = bid < npatch_blocks;
    int n = is_patch ? (bid / 3) : (bid - npatch_blocks);

    if (tid == 0) {
        double a = (double)angles[n];
        prm[0] = (float)cos(a);             // correctly-rounded f32
        prm[1] = (float)sin(a);
        prm[2] = flip_h[n] ? -1.0f : 1.0f;
        prm[3] = flip_v[n] ? -1.0f : 1.0f;
        prm[4] = scales[n];
    }
    __syncthreads();
    float c = prm[0], s = prm[1], fsx = prm[2], fsy = prm[3], sc = prm[4];

    int w = tid & (WW - 1);

    if (is_patch) {
        int slice = bid;                    // n*3 + ch

        // ---- stage full slice coalesced (float4, exactly 1x fetch) ----
        const float4* g4 = (const float4*)(patches + (size_t)slice * HW);
        float4* s4 = (float4*)src;
        #pragma unroll
        for (int i = 0; i < HW / 4 / 1024; ++i)      // 4 iters
            s4[i * 1024 + tid] = g4[i * 1024 + tid];
        __syncthreads();

        // per-lane invariants: pass-1 x-side
        float x1n = __fmul_rn(fsx, norm_coord(w));   // exact sign flip
        float cx = __fmul_rn(c, x1n);
        float sx = __fmul_rn(s, x1n);
        // per-lane invariants: pass-2 x-side
        float ixo = pix_coord(__fmul_rn(sc, norm_coord(w)));
        float x0fo = floorf(ixo);
        float wx1o = __fsub_rn(ixo, x0fo);
        float wx0o = __fsub_rn(1.0f, wx1o);
        int x0o = (int)x0fo, x1o = x0o + 1;
        bool bx0o = (unsigned)x0o < 128u, bx1o = (unsigned)x1o < 128u;
        int xc0o = clamp127(x0o), xc1o = clamp127(x1o);

        float* op = out_p + (size_t)slice * HW;

        for (int band = 0; band < HH / BAND; ++band) {       // 8 bands
            int r0 = band * BAND;
            float iy_lo = pix_coord(__fmul_rn(sc, norm_coord(r0)));
            float iy_hi = pix_coord(__fmul_rn(sc, norm_coord(r0 + BAND - 1)));
            int lo = (int)floorf(iy_lo);
            int hi = (int)floorf(iy_hi) + 1;
            lo = lo < 0 ? 0 : lo;
            hi = hi > 127 ? 127 : hi;
            int nrows = hi - lo + 1;                         // <= 19

            // ---- pass 1: rotate+flip from LDS src -> tile ----
            #pragma unroll
            for (int i = 0; i < 3; ++i) {                    // ceil(19*128/1024)
                int p = i * 1024 + tid;
                int row = p >> 7;
                if (row < nrows) {
                    int h = lo + row;
                    float y = __fmul_rn(fsy, norm_coord(h));
                    float ix = pix_coord(__fmaf_rn(-s, y, cx));
                    float iy = pix_coord(__fmaf_rn(c, y, sx));
                    float x0f = floorf(ix), y0f = floorf(iy);
                    float wx1 = __fsub_rn(ix, x0f), wy1 = __fsub_rn(iy, y0f);
                    float wx0 = __fsub_rn(1.0f, wx1), wy0 = __fsub_rn(1.0f, wy1);
                    int x0 = (int)x0f, y0 = (int)y0f;
                    int x1 = x0 + 1, y1 = y0 + 1;
                    bool bx0 = (unsigned)x0 < 128u, bx1 = (unsigned)x1 < 128u;
                    bool by0 = (unsigned)y0 < 128u, by1 = (unsigned)y1 < 128u;
                    int xc0 = clamp127(x0), xc1 = clamp127(x1);
                    int yc0 = clamp127(y0) * WW, yc1 = clamp127(y1) * WW;
                    float v00 = src[yc0 + xc0];
                    float v10 = src[yc0 + xc1];
                    float v01 = src[yc1 + xc0];
                    float v11 = src[yc1 + xc1];
                    v00 = (bx0 && by0) ? v00 : 0.0f;
                    v10 = (bx1 && by0) ? v10 : 0.0f;
                    v01 = (bx0 && by1) ? v01 : 0.0f;
                    v11 = (bx1 && by1) ? v11 : 0.0f;
                    float acc;
                    acc = __fmul_rn(v00, __fmul_rn(wx0, wy0));
                    acc = __fadd_rn(acc, __fmul_rn(v10, __fmul_rn(wx1, wy0)));
                    acc = __fadd_rn(acc, __fmul_rn(v01, __fmul_rn(wx0, wy1)));
                    acc = __fadd_rn(acc, __fmul_rn(v11, __fmul_rn(wx1, wy1)));
                    tile[row * WW + w] = acc;
                }
            }
            __syncthreads();

            // ---- pass 2: scale from tile -> out rows [r0, r0+16) ----
            #pragma unroll
            for (int i = 0; i < 2; ++i) {
                int p = i * 1024 + tid;
                int row = p >> 7;
                int h = r0 + row;
                float iy = pix_coord(__fmul_rn(sc, norm_coord(h)));
                float y0f = floorf(iy);
                float wy1 = __fsub_rn(iy, y0f);
                float wy0 = __fsub_rn(1.0f, wy1);
                float w00 = __fmul_rn(wx0o, wy0), w10 = __fmul_rn(wx1o, wy0);
                float w01 = __fmul_rn(wx0o, wy1), w11 = __fmul_rn(wx1o, wy1);
                int y0 = (int)y0f, y1 = y0 + 1;
                bool by0 = (unsigned)y0 < 128u, by1 = (unsigned)y1 < 128u;
                int t0 = (iclamp(y0, lo, hi) - lo) * WW;
                int t1 = (iclamp(y1, lo, hi) - lo) * WW;
                float v00 = tile[t0 + xc0o];
                float v10 = tile[t0 + xc1o];
                float v01 = tile[t1 + xc0o];
                float v11 = tile[t1 + xc1o];
                v00 = (bx0o && by0) ? v00 : 0.0f;
                v10 = (bx1o && by0) ? v10 : 0.0f;
                v01 = (bx0o && by1) ? v01 : 0.0f;
                v11 = (bx1o && by1) ? v11 : 0.0f;
                float acc;
                acc = __fmul_rn(v00, w00);
                acc = __fadd_rn(acc, __fmul_rn(v10, w10));
                acc = __fadd_rn(acc, __fmul_rn(v01, w01));
                acc = __fadd_rn(acc, __fmul_rn(v11, w11));
                op[r0 * WW + row * WW + w] = acc;
            }
            __syncthreads();   // tile reused by next band
        }
    } else {
        // ----- label path: fused nearest-of-nearest, one slice per block -----
        const float* lab = labels + (size_t)n * HW;
        float* ol = out_l + (size_t)n * HW;

        float ix2 = pix_coord(__fmul_rn(sc, norm_coord(w)));
        float xr2 = rintf(ix2);
        bool okx2 = (xr2 >= 0.0f) && (xr2 <= 127.0f);
        int w2 = (int)xr2;
        float xw2 = okx2 ? __fmul_rn(fsx, norm_coord(w2)) : 0.0f;
        float cx = __fmul_rn(c, xw2);
        float sx = __fmul_rn(s, xw2);

        #pragma unroll 4
        for (int i = 0; i < HW / 1024; ++i) {        // 16 iters
            int p = i * 1024 + tid;
            int h = p >> 7;
            float iy2 = pix_coord(__fmul_rn(sc, norm_coord(h)));
            float yr2 = rintf(iy2);
            float outv = 0.0f;
            if (okx2 && yr2 >= 0.0f && yr2 <= 127.0f) {
                int h2 = (int)yr2;
                float y = __fmul_rn(fsy, norm_coord(h2));
                float xr1 = rintf(pix_coord(__fmaf_rn(-s, y, cx)));
                float yr1 = rintf(pix_coord(__fmaf_rn(c, y, sx)));
                if (xr1 >= 0.0f && xr1 <= 127.0f &&
                    yr1 >= 0.0f && yr1 <= 127.0f) {
                    outv = lab[(int)yr1 * WW + (int)xr1];
                }
            }
            ol[p] = outv;
        }
    }
}

extern "C" void kernel_launch(void* const* d_in, const int* in_sizes, int n_in,
                              void* d_out, int out_size, void* d_ws, size_t ws_size,
                              hipStream_t stream) {
    const float* patches = (const float*)d_in[0];
    const float* labels  = (const float*)d_in[1];
    const float* angles  = (const float*)d_in[2];
    const int*   flip_h  = (const int*)d_in[3];
    const int*   flip_v  = (const int*)d_in[4];
    const float* scales  = (const float*)d_in[5];

    const int N = in_sizes[2];            // B*K = 256
    float* out   = (float*)d_out;
    float* out_p = out;                   // N*3*H*W
    float* out_l = out + (size_t)N * 3 * HW;

    int npatch_blocks = N * 3;            // 768: one per channel slice
    int nlabel_blocks = N;                // 256: one per label slice
    pa_all<<<npatch_blocks + nlabel_blocks, 1024, 0, stream>>>(
        patches, labels, angles, flip_h, flip_v, scales,
        out_p, out_l, npatch_blocks);
}

// Round 17
// 40.481 us; speedup vs baseline: 1.6308x; 1.2511x over previous
//
#include <hip/hip_runtime.h>

// Problem constants (B=8, K=32 -> N=256 patches; C=3; H=W=128)
#define HH 128
#define WW 128
#define HW (HH * WW)
#define BAND 16            // output rows per band
#define TROWS 20           // intermediate tile rows (max needed ~18)

// ---------------------------------------------------------------------------
// Correctness split (R9-R16 verified):
//  - LABELS (nearest): discontinuous decisions -> keep the bit-exact chain:
//    CR f32 trig, XLA-FMA rotation lowering, stepwise pix chain, rintf.
//  - PATCHES (bilinear): Lipschitz in coords; threshold 0.069 vs current
//    0.0156 -> fast affine coordinate forms (ix = fmaf(B,h,A)) are safe
//    (<=2e-5 px coord error -> <=1e-4 value error).
// Structure (R16, verified): full 64 KB slice staged to LDS once (1x fetch),
// 8 banded pass-1/pass-2 rounds from LDS. This round: VALU diet on the patch
// path (affine coords, masked weights, med3 clamps, 6-op accumulation,
// 2px/thread pass-2 with float2 stores).
// ---------------------------------------------------------------------------

__device__ __forceinline__ float norm_coord(int i) {
    return __fsub_rn(__fmul_rn((float)(2 * i + 1), 0.0078125f), 1.0f);
}

__device__ __forceinline__ float pix_coord(float g) {
    float t = __fadd_rn(g, 1.0f);
    t = __fmul_rn(t, 128.0f);
    t = __fsub_rn(t, 1.0f);
    return __fmul_rn(t, 0.5f);
}

__device__ __forceinline__ int med127(int v) {
    return min(max(v, 0), 127);     // -> v_med3_i32
}

// ---------------------------------------------------------------------------
// Blocks [0, NP): one per channel slice (1024 thr). Blocks [NP, NP+N):
// one per label slice. Branch is block-uniform.
// ---------------------------------------------------------------------------
__global__ void __launch_bounds__(1024, 8)
pa_all(const float* __restrict__ patches,
       const float* __restrict__ labels,
       const float* __restrict__ angles,
       const int* __restrict__ flip_h,
       const int* __restrict__ flip_v,
       const float* __restrict__ scales,
       float* __restrict__ out_p,
       float* __restrict__ out_l,
       int npatch_blocks) {
    __shared__ float src[HW];               // 64 KB full source slice
    __shared__ float tile[TROWS * WW];      // 10 KB pass-1 intermediate band
    __shared__ float prm[5];
    int bid = blockIdx.x;
    int tid = threadIdx.x;
    bool is_patch = bid < npatch_blocks;
    int n = is_patch ? (bid / 3) : (bid - npatch_blocks);

    if (tid == 0) {
        double a = (double)angles[n];
        prm[0] = (float)cos(a);             // correctly-rounded f32
        prm[1] = (float)sin(a);
        prm[2] = flip_h[n] ? -1.0f : 1.0f;
        prm[3] = flip_v[n] ? -1.0f : 1.0f;
        prm[4] = scales[n];
    }
    __syncthreads();
    float c = prm[0], s = prm[1], fsx = prm[2], fsy = prm[3], sc = prm[4];

    if (is_patch) {
        int slice = bid;                    // n*3 + ch

        // ---- stage full slice coalesced (float4, exactly 1x fetch) ----
        const float4* g4 = (const float4*)(patches + (size_t)slice * HW);
        float4* s4 = (float4*)src;
        #pragma unroll
        for (int i = 0; i < HW / 4 / 1024; ++i)      // 4 iters
            s4[i * 1024 + tid] = g4[i * 1024 + tid];

        // ---- per-lane hoists (fast math; patches only) ----
        int w = tid & (WW - 1);
        float nx = fmaf((float)(2 * w + 1), 0.0078125f, -1.0f);
        float xw = fsx * nx;
        float cx = c * xw, sxw = s * xw;
        float sfsy = s * fsy, cfsy = c * fsy;
        // pass-1 affine coords: ix = Ax + Bx*h, iy = Ay + By*h
        float Ax = fmaf(sfsy, 63.5f, fmaf(64.0f, cx, 63.5f));
        float Bx = -sfsy;
        float Ay = fmaf(cfsy, -63.5f, fmaf(64.0f, sxw, 63.5f));
        float By = cfsy;
        // pass-2 y affine: iy = sc*h + Cy
        float Cy = fmaf(-63.5f, sc, 63.5f);

        // pass-2 2px/thread x-side hoists: w0 = 2*(tid&63), w1 = w0+1
        int wp = tid & 63;
        int w0 = wp * 2;
        float wx0a, wx1a, wx0b, wx1b;
        int xc0a, xc1a, xc0b, xc1b;
        {
            float nxa = fmaf((float)(2 * w0 + 1), 0.0078125f, -1.0f);
            float ixo = fmaf(64.0f * sc, nxa, 63.5f);
            float x0f = floorf(ixo);
            float fx = ixo - x0f;
            int xi = (int)x0f;
            wx0a = ((unsigned)xi < 128u) ? (1.0f - fx) : 0.0f;
            wx1a = ((unsigned)(xi + 1) < 128u) ? fx : 0.0f;
            xc0a = med127(xi); xc1a = med127(xi + 1);
        }
        {
            float nxb = fmaf((float)(2 * (w0 + 1) + 1), 0.0078125f, -1.0f);
            float ixo = fmaf(64.0f * sc, nxb, 63.5f);
            float x0f = floorf(ixo);
            float fx = ixo - x0f;
            int xi = (int)x0f;
            wx0b = ((unsigned)xi < 128u) ? (1.0f - fx) : 0.0f;
            wx1b = ((unsigned)(xi + 1) < 128u) ? fx : 0.0f;
            xc0b = med127(xi); xc1b = med127(xi + 1);
        }
        int prow = tid >> 6;                // pass-2 row 0..15 within band
        __syncthreads();

        float* op = out_p + (size_t)slice * HW;

        #pragma unroll
        for (int band = 0; band < HH / BAND; ++band) {       // 8 bands
            int r0 = band * BAND;
            // band row range from the SAME fast chain as pass-2 (monotone)
            int lo = max((int)floorf(fmaf(sc, (float)r0, Cy)), 0);
            int hi = min((int)floorf(fmaf(sc, (float)(r0 + BAND - 1), Cy)) + 1, 127);
            int nrows = hi - lo + 1;                         // <= 18

            // ---- pass 1: rotate+flip from LDS src -> tile ----
            #pragma unroll
            for (int i = 0; i < 3; ++i) {
                int row = i * 8 + (tid >> 7);
                if (row < nrows) {
                    float hf = (float)(lo + row);
                    float ix = fmaf(Bx, hf, Ax);
                    float iy = fmaf(By, hf, Ay);
                    float x0f = floorf(ix), y0f = floorf(iy);
                    float fx = ix - x0f, fy = iy - y0f;
                    int xi = (int)x0f, yi = (int)y0f;
                    float wx0 = ((unsigned)xi < 128u) ? (1.0f - fx) : 0.0f;
                    float wx1 = ((unsigned)(xi + 1) < 128u) ? fx : 0.0f;
                    float wy0 = ((unsigned)yi < 128u) ? (1.0f - fy) : 0.0f;
                    float wy1 = ((unsigned)(yi + 1) < 128u) ? fy : 0.0f;
                    int xc0 = med127(xi), xc1 = med127(xi + 1);
                    int b0 = med127(yi) * WW, b1 = med127(yi + 1) * WW;
                    float v00 = src[b0 + xc0];
                    float v10 = src[b0 + xc1];
                    float v01 = src[b1 + xc0];
                    float v11 = src[b1 + xc1];
                    float ra = fmaf(wx1, v10, wx0 * v00);
                    float rb = fmaf(wx1, v11, wx0 * v01);
                    tile[row * WW + w] = fmaf(rb, wy1, ra * wy0);
                }
            }
            __syncthreads();

            // ---- pass 2: scale from tile, 2 px/thread, float2 store ----
            {
                int h = r0 + prow;
                float iy = fmaf(sc, (float)h, Cy);
                float y0f = floorf(iy);
                float fy = iy - y0f;
                int yi = (int)y0f;
                float wy0 = ((unsigned)yi < 128u) ? (1.0f - fy) : 0.0f;
                float wy1 = ((unsigned)(yi + 1) < 128u) ? fy : 0.0f;
                int t0 = (min(max(yi, lo), hi) - lo) * WW;
                int t1 = (min(max(yi + 1, lo), hi) - lo) * WW;
                float v00a = tile[t0 + xc0a];
                float v10a = tile[t0 + xc1a];
                float v01a = tile[t1 + xc0a];
                float v11a = tile[t1 + xc1a];
                float v00b = tile[t0 + xc0b];
                float v10b = tile[t0 + xc1b];
                float v01b = tile[t1 + xc0b];
                float v11b = tile[t1 + xc1b];
                float raa = fmaf(wx1a, v10a, wx0a * v00a);
                float rba = fmaf(wx1a, v11a, wx0a * v01a);
                float rab = fmaf(wx1b, v10b, wx0b * v00b);
                float rbb = fmaf(wx1b, v11b, wx0b * v01b);
                float2 o;
                o.x = fmaf(rba, wy1, raa * wy0);
                o.y = fmaf(rbb, wy1, rab * wy0);
                *(float2*)&op[h * WW + w0] = o;
            }
            __syncthreads();   // tile reused by next band
        }
    } else {
        // ----- label path: BIT-EXACT fused nearest-of-nearest (R9 chain) -----
        const float* lab = labels + (size_t)n * HW;
        float* ol = out_l + (size_t)n * HW;
        int w = tid & (WW - 1);

        float ix2 = pix_coord(__fmul_rn(sc, norm_coord(w)));
        float xr2 = rintf(ix2);
        bool okx2 = (xr2 >= 0.0f) && (xr2 <= 127.0f);
        int w2 = (int)xr2;
        float xw2 = okx2 ? __fmul_rn(fsx, norm_coord(w2)) : 0.0f;
        float cx = __fmul_rn(c, xw2);
        float sx = __fmul_rn(s, xw2);

        #pragma unroll 4
        for (int i = 0; i < HW / 1024; ++i) {        // 16 iters
            int p = i * 1024 + tid;
            int h = p >> 7;
            float iy2 = pix_coord(__fmul_rn(sc, norm_coord(h)));
            float yr2 = rintf(iy2);
            float outv = 0.0f;
            if (okx2 && yr2 >= 0.0f && yr2 <= 127.0f) {
                int h2 = (int)yr2;
                float y = __fmul_rn(fsy, norm_coord(h2));
                float xr1 = rintf(pix_coord(__fmaf_rn(-s, y, cx)));
                float yr1 = rintf(pix_coord(__fmaf_rn(c, y, sx)));
                if (xr1 >= 0.0f && xr1 <= 127.0f &&
                    yr1 >= 0.0f && yr1 <= 127.0f) {
                    outv = lab[(int)yr1 * WW + (int)xr1];
                }
            }
            ol[p] = outv;
        }
    }
}

extern "C" void kernel_launch(void* const* d_in, const int* in_sizes, int n_in,
                              void* d_out, int out_size, void* d_ws, size_t ws_size,
                              hipStream_t stream) {
    const float* patches = (const float*)d_in[0];
    const float* labels  = (const float*)d_in[1];
    const float* angles  = (const float*)d_in[2];
    const int*   flip_h  = (const int*)d_in[3];
    const int*   flip_v  = (const int*)d_in[4];
    const float* scales  = (const float*)d_in[5];

    const int N = in_sizes[2];            // B*K = 256
    float* out   = (float*)d_out;
    float* out_p = out;                   // N*3*H*W
    float* out_l = out + (size_t)N * 3 * HW;

    int npatch_blocks = N * 3;            // 768: one per channel slice
    int nlabel_blocks = N;                // 256: one per label slice
    pa_all<<<npatch_blocks + nlabel_blocks, 1024, 0, stream>>>(
        patches, labels, angles, flip_h, flip_v, scales,
        out_p, out_l, npatch_blocks);
}

// Round 18
// 40.291 us; speedup vs baseline: 1.6385x; 1.0047x over previous
//
#include <hip/hip_runtime.h>

// Problem constants (B=8, K=32 -> N=256 patches; C=3; H=W=128)
#define HH 128
#define WW 128
#define HW (HH * WW)
#define BAND 16            // output rows per band
#define TROWS 18           // intermediate tile rows (nrows <= 18 proven)

// ---------------------------------------------------------------------------
// Correctness split (R9-R17 verified):
//  - LABELS (nearest): bit-exact chain (CR f32 trig, XLA-FMA rotation,
//    stepwise pix chain, rintf). UNTOUCHED.
//  - PATCHES (bilinear): Lipschitz in coords; fast affine forms safe
//    (absmax 0.0156 vs threshold 0.0694).
// Structure (R16/R17): full 64 KB slice in LDS (1x fetch), 8 banded passes.
// This round: adjacent-pair tap loads (ds_read2_b32 formation) + 2px/thread
// pass-1 with float2 tile writes -> ~halves LDS instruction count.
// Pair trick: load (xb, xb+1) with xb=med127(xi); v0=pa, v1=(xi>=0)?pb:pa.
//   xi=-1: v1=pa=px0 (correct; v0 masked). xi=127: pb spills into tile[]
//   (defined LDS, weight-masked 0). xi in [0,126]: exact taps.
// ---------------------------------------------------------------------------

__device__ __forceinline__ float norm_coord(int i) {
    return __fsub_rn(__fmul_rn((float)(2 * i + 1), 0.0078125f), 1.0f);
}

__device__ __forceinline__ float pix_coord(float g) {
    float t = __fadd_rn(g, 1.0f);
    t = __fmul_rn(t, 128.0f);
    t = __fsub_rn(t, 1.0f);
    return __fmul_rn(t, 0.5f);
}

__device__ __forceinline__ int med127(int v) {
    return min(max(v, 0), 127);     // -> v_med3_i32
}

// ---------------------------------------------------------------------------
// Blocks [0, NP): one per channel slice (1024 thr). Blocks [NP, NP+N):
// one per label slice. Branch is block-uniform.
// ---------------------------------------------------------------------------
__global__ void __launch_bounds__(1024, 8)
pa_all(const float* __restrict__ patches,
       const float* __restrict__ labels,
       const float* __restrict__ angles,
       const int* __restrict__ flip_h,
       const int* __restrict__ flip_v,
       const float* __restrict__ scales,
       float* __restrict__ out_p,
       float* __restrict__ out_l,
       int npatch_blocks) {
    __shared__ float src[HW];               // 64 KB full source slice
    __shared__ float tile[TROWS * WW];      // 9 KB pass-1 intermediate band
    __shared__ float prm[5];
    int bid = blockIdx.x;
    int tid = threadIdx.x;
    bool is_patch = bid < npatch_blocks;
    int n = is_patch ? (bid / 3) : (bid - npatch_blocks);

    if (tid == 0) {
        double a = (double)angles[n];
        prm[0] = (float)cos(a);             // correctly-rounded f32
        prm[1] = (float)sin(a);
        prm[2] = flip_h[n] ? -1.0f : 1.0f;
        prm[3] = flip_v[n] ? -1.0f : 1.0f;
        prm[4] = scales[n];
    }
    __syncthreads();
    float c = prm[0], s = prm[1], fsx = prm[2], fsy = prm[3], sc = prm[4];

    if (is_patch) {
        int slice = bid;                    // n*3 + ch

        // ---- stage full slice coalesced (float4, exactly 1x fetch) ----
        const float4* g4 = (const float4*)(patches + (size_t)slice * HW);
        float4* s4 = (float4*)src;
        #pragma unroll
        for (int i = 0; i < HW / 4 / 1024; ++i)      // 4 iters
            s4[i * 1024 + tid] = g4[i * 1024 + tid];

        // ---- per-lane hoists (fast affine coords; patches only) ----
        int w2 = (tid & 63) * 2;            // 2 adjacent px per thread
        float nx = fmaf((float)(2 * w2 + 1), 0.0078125f, -1.0f);
        float xw = fsx * nx;
        float cx = c * xw, sxw = s * xw;
        float sfsy = s * fsy, cfsy = c * fsy;
        float Cx = c * fsx;                 // d(ix)/dw
        float Sx = s * fsx;                 // d(iy)/dw
        // pass-1 affine: ix = Ax + Bx*h (for px w2), ix(w2+1) = ix + Cx
        float Ax = fmaf(sfsy, 63.5f, fmaf(64.0f, cx, 63.5f));
        float Bx = -sfsy;
        float Ay = fmaf(cfsy, -63.5f, fmaf(64.0f, sxw, 63.5f));
        float By = cfsy;
        // pass-2 y affine: iy = sc*h + Cy
        float Cy = fmaf(-63.5f, sc, 63.5f);

        // pass-2 x-side hoists for px (w2, w2+1): pair bases + weights
        float wx0a, wx1a, wx0b, wx1b;
        int xba, xbb;
        bool pxa, pxb;                      // xi >= 0 (pair-select bits)
        {
            float ixo = fmaf(64.0f * sc, nx, 63.5f);
            float x0f = floorf(ixo);
            float fx = ixo - x0f;
            int xi = (int)x0f;
            wx0a = ((unsigned)xi < 128u) ? (1.0f - fx) : 0.0f;
            wx1a = ((unsigned)(xi + 1) < 128u) ? fx : 0.0f;
            xba = med127(xi); pxa = xi >= 0;
            float ixo2 = ixo + sc;          // next px: +d(ix)/dw = sc
            float x0f2 = floorf(ixo2);
            float fx2 = ixo2 - x0f2;
            int xi2 = (int)x0f2;
            wx0b = ((unsigned)xi2 < 128u) ? (1.0f - fx2) : 0.0f;
            wx1b = ((unsigned)(xi2 + 1) < 128u) ? fx2 : 0.0f;
            xbb = med127(xi2); pxb = xi2 >= 0;
        }
        int prow = tid >> 6;                // pass-2 row 0..15 within band
        __syncthreads();

        float* op = out_p + (size_t)slice * HW;

        #pragma unroll
        for (int band = 0; band < HH / BAND; ++band) {       // 8 bands
            int r0 = band * BAND;
            int lo = max((int)floorf(fmaf(sc, (float)r0, Cy)), 0);
            int hi = min((int)floorf(fmaf(sc, (float)(r0 + BAND - 1), Cy)) + 1, 127);
            int nrows = hi - lo + 1;                         // <= 18

            // ---- pass 1: rotate+flip from LDS src -> tile (2 px/thread) ----
            #pragma unroll
            for (int it = 0; it < 2; ++it) {                 // 16 rows, then 2
                int row = it * 16 + (tid >> 6);
                if (row < nrows) {
                    float hf = (float)(lo + row);
                    float ixa = fmaf(Bx, hf, Ax);
                    float iya = fmaf(By, hf, Ay);
                    float o01[2];
                    float ix = ixa, iy = iya;
                    #pragma unroll
                    for (int px = 0; px < 2; ++px) {
                        float x0f = floorf(ix), y0f = floorf(iy);
                        float fx = ix - x0f, fy = iy - y0f;
                        int xi = (int)x0f, yi = (int)y0f;
                        float wx0 = ((unsigned)xi < 128u) ? (1.0f - fx) : 0.0f;
                        float wx1 = ((unsigned)(xi + 1) < 128u) ? fx : 0.0f;
                        float wy0 = ((unsigned)yi < 128u) ? (1.0f - fy) : 0.0f;
                        float wy1 = ((unsigned)(yi + 1) < 128u) ? fy : 0.0f;
                        int xb = med127(xi);
                        bool ps = xi >= 0;
                        const float* r0p = &src[med127(yi) * WW + xb];
                        const float* r1p = &src[med127(yi + 1) * WW + xb];
                        float p0a = r0p[0], p0b = r0p[1];    // ds_read2_b32
                        float p1a = r1p[0], p1b = r1p[1];    // ds_read2_b32
                        float v10 = ps ? p0b : p0a;
                        float v11 = ps ? p1b : p1a;
                        float ra = fmaf(wx1, v10, wx0 * p0a);
                        float rb = fmaf(wx1, v11, wx0 * p1a);
                        o01[px] = fmaf(rb, wy1, ra * wy0);
                        ix += Cx; iy += Sx;
                    }
                    *(float2*)&tile[row * WW + w2] = make_float2(o01[0], o01[1]);
                }
            }
            __syncthreads();

            // ---- pass 2: scale from tile, 2 px/thread, float2 store ----
            {
                int h = r0 + prow;
                float iy = fmaf(sc, (float)h, Cy);
                float y0f = floorf(iy);
                float fy = iy - y0f;
                int yi = (int)y0f;
                float wy0 = ((unsigned)yi < 128u) ? (1.0f - fy) : 0.0f;
                float wy1 = ((unsigned)(yi + 1) < 128u) ? fy : 0.0f;
                int t0 = (min(max(yi, lo), hi) - lo) * WW;
                int t1 = (min(max(yi + 1, lo), hi) - lo) * WW;
                const float* ta0 = &tile[t0 + xba];
                const float* ta1 = &tile[t1 + xba];
                const float* tb0 = &tile[t0 + xbb];
                const float* tb1 = &tile[t1 + xbb];
                float a0a = ta0[0], a0b = ta0[1];            // ds_read2_b32
                float a1a = ta1[0], a1b = ta1[1];
                float b0a = tb0[0], b0b = tb0[1];
                float b1a = tb1[0], b1b = tb1[1];
                float v10a = pxa ? a0b : a0a;
                float v11a = pxa ? a1b : a1a;
                float v10b = pxb ? b0b : b0a;
                float v11b = pxb ? b1b : b1a;
                float raa = fmaf(wx1a, v10a, wx0a * a0a);
                float rba = fmaf(wx1a, v11a, wx0a * a1a);
                float rab = fmaf(wx1b, v10b, wx0b * b0a);
                float rbb = fmaf(wx1b, v11b, wx0b * b1a);
                float2 o;
                o.x = fmaf(rba, wy1, raa * wy0);
                o.y = fmaf(rbb, wy1, rab * wy0);
                *(float2*)&op[h * WW + w2] = o;
            }
            __syncthreads();   // tile reused by next band
        }
    } else {
        // ----- label path: BIT-EXACT fused nearest-of-nearest (R9 chain) -----
        const float* lab = labels + (size_t)n * HW;
        float* ol = out_l + (size_t)n * HW;
        int w = tid & (WW - 1);

        float ix2 = pix_coord(__fmul_rn(sc, norm_coord(w)));
        float xr2 = rintf(ix2);
        bool okx2 = (xr2 >= 0.0f) && (xr2 <= 127.0f);
        int w2 = (int)xr2;
        float xw2 = okx2 ? __fmul_rn(fsx, norm_coord(w2)) : 0.0f;
        float cx = __fmul_rn(c, xw2);
        float sx = __fmul_rn(s, xw2);

        #pragma unroll 4
        for (int i = 0; i < HW / 1024; ++i) {        // 16 iters
            int p = i * 1024 + tid;
            int h = p >> 7;
            float iy2 = pix_coord(__fmul_rn(sc, norm_coord(h)));
            float yr2 = rintf(iy2);
            float outv = 0.0f;
            if (okx2 && yr2 >= 0.0f && yr2 <= 127.0f) {
                int h2 = (int)yr2;
                float y = __fmul_rn(fsy, norm_coord(h2));
                float xr1 = rintf(pix_coord(__fmaf_rn(-s, y, cx)));
                float yr1 = rintf(pix_coord(__fmaf_rn(c, y, sx)));
                if (xr1 >= 0.0f && xr1 <= 127.0f &&
                    yr1 >= 0.0f && yr1 <= 127.0f) {
                    outv = lab[(int)yr1 * WW + (int)xr1];
                }
            }
            ol[p] = outv;
        }
    }
}

extern "C" void kernel_launch(void* const* d_in, const int* in_sizes, int n_in,
                              void* d_out, int out_size, void* d_ws, size_t ws_size,
                              hipStream_t stream) {
    const float* patches = (const float*)d_in[0];
    const float* labels  = (const float*)d_in[1];
    const float* angles  = (const float*)d_in[2];
    const int*   flip_h  = (const int*)d_in[3];
    const int*   flip_v  = (const int*)d_in[4];
    const float* scales  = (const float*)d_in[5];

    const int N = in_sizes[2];            // B*K = 256
    float* out   = (float*)d_out;
    float* out_p = out;                   // N*3*H*W
    float* out_l = out + (size_t)N * 3 * HW;

    int npatch_blocks = N * 3;            // 768: one per channel slice
    int nlabel_blocks = N;                // 256: one per label slice
    pa_all<<<npatch_blocks + nlabel_blocks, 1024, 0, stream>>>(
        patches, labels, angles, flip_h, flip_v, scales,
        out_p, out_l, npatch_blocks);
}